// Round 7
// baseline (237.474 us; speedup 1.0000x reference)
//
#include <hip/hip_runtime.h>

// Multi-threshold spiking neuron scan. x: [T*B, C, H, W] fp32, T=4, K=8.
// Per column: mem += x[t]; spike = largest thre[k]=thresh/2^k with
// mem >= 0.75*thre[k]; out[t] = spike; mem -= spike.
//
// R1-R5: five structurally different kernels pinned at ~88us / 2.3 TB/s.
// R6: XCD-segmented j-sweep, BLOCK=256: kernel ~79us (2.5 TB/s). Best.
// R7 FAILED (126us): per-thread 4-col chunk; pipeline collapsed + no TLP.
// R8 FAILED (88us): BLOCK=1024 alone.
// R9 NULL (80.5us): 4KiB/stream alias-breaking rotation via LDS. Address
//   aliasing between the 8 x/out streams is NOT the wall.
// R10 (this): R6 verbatim, ONE variable flipped — regular stores instead of
//   __builtin_nontemporal_store. Every 2.5 TB/s measurement this session had
//   NT stores; every 5-6.7 TB/s reference (fill, copy ubench, RMSNorm) used
//   regular stores. Tests whether gfx950 NT write path (no-L2-allocate
//   streaming) throttles the memory pipe. Pre-committed probe from R5.

constexpr int T_STEPS = 4;
constexpr int BLOCK = 256;
constexpr int NXCD = 8;

typedef float v4f __attribute__((ext_vector_type(4)));

// Exact spike via fp32 bit ordering (thresh > 0 normal, mem non-NaN):
// positive fp32 compare == int compare of bits; thr75[k] bits = b75_0 - k*2^23;
// k* = max(0, ceil((b75_0 - bits(mem)) / 2^23)); spike bits = bth0 - k*·2^23;
// mem < thr75[7] (incl. mem<=0, signed cmp) -> 0.  Verified absmax=0 R5-R9.
__device__ __forceinline__ float spike_of(float mem, int b75_0, int b75_7, int bth0) {
    int u = __float_as_int(mem);
    int d = (int)((unsigned)b75_0 - (unsigned)u);
    int k = (int)((unsigned)d + 0x7fffffu) >> 23;
    k = k > 0 ? k : 0;
    int sb = bth0 - (k << 23);
    return (u >= b75_7) ? __int_as_float(sb) : 0.0f;
}

__global__ __launch_bounds__(BLOCK) void snn_mth_kernel(
    const float* __restrict__ x,
    const float* __restrict__ p_thresh,
    float* __restrict__ out,
    int s4)   // float4 columns per timestep
{
    const float thresh = *p_thresh;
    const int bth0  = __float_as_int(thresh);
    const int b75_0 = __float_as_int(0.75f * thresh);
    const int b75_7 = b75_0 - 7 * 0x800000;

    const v4f* __restrict__ xv = reinterpret_cast<const v4f*>(x);
    v4f* __restrict__ ov = reinterpret_cast<v4f*>(out);

    // XCD-segmented mapping (R6): segment = b % NXCD (matches CP round-robin
    // block->XCD dispatch), slot = b / NXCD sweeps within the segment.
    const int seg_cols   = s4 / (NXCD * BLOCK) * BLOCK;  // cols per segment (whole blocks)
    const int seg_blocks = seg_cols / BLOCK;
    const int main_blocks = seg_blocks * NXCD;

    const int b = blockIdx.x;
    size_t j;
    if (b < main_blocks) {
        const int xcd  = b % NXCD;
        const int slot = b / NXCD;
        j = (size_t)xcd * seg_cols + (size_t)slot * BLOCK + threadIdx.x;
    } else {
        // Tail (empty for the benchmark shape: s4 = 2^21 divides evenly).
        j = (size_t)NXCD * seg_cols + (size_t)(b - main_blocks) * BLOCK + threadIdx.x;
        if (j >= (size_t)s4) return;
    }

    const size_t n = (size_t)s4;

    v4f xc[T_STEPS];
#pragma unroll
    for (int t = 0; t < T_STEPS; ++t)
        xc[t] = xv[(size_t)t * n + j];

    v4f sp[T_STEPS];
#pragma unroll
    for (int e = 0; e < 4; ++e) {
        float mem = xc[0][e];
        float s0 = spike_of(mem, b75_0, b75_7, bth0);
        sp[0][e] = s0;
        mem = mem - s0 + xc[1][e];
        float s1 = spike_of(mem, b75_0, b75_7, bth0);
        sp[1][e] = s1;
        mem = mem - s1 + xc[2][e];
        float s2 = spike_of(mem, b75_0, b75_7, bth0);
        sp[2][e] = s2;
        mem = mem - s2 + xc[3][e];
        sp[3][e] = spike_of(mem, b75_0, b75_7, bth0);
    }

#pragma unroll
    for (int t = 0; t < T_STEPS; ++t)
        ov[(size_t)t * n + j] = sp[t];   // regular store (R10: NT removed)
}

extern "C" void kernel_launch(void* const* d_in, const int* in_sizes, int n_in,
                              void* d_out, int out_size, void* d_ws, size_t ws_size,
                              hipStream_t stream) {
    const float* x = (const float*)d_in[0];
    const float* p_thresh = (const float*)d_in[1];
    float* out = (float*)d_out;

    const int total = in_sizes[0];          // T*B*C*H*W
    const int S = total / T_STEPS;          // spatial elements per timestep
    const int s4 = S >> 2;                  // float4 columns

    const int grid = (s4 + BLOCK - 1) / BLOCK;
    snn_mth_kernel<<<grid, BLOCK, 0, stream>>>(x, p_thresh, out, s4);
}

// Round 9
// 235.209 us; speedup vs baseline: 1.0096x; 1.0096x over previous
//
#include <hip/hip_runtime.h>

// Multi-threshold spiking neuron scan. x: [T*B, C, H, W] fp32, T=4, K=8.
// Per column: mem += x[t]; spike = largest thre[k]=thresh/2^k with
// mem >= 0.75*thre[k]; out[t] = spike; mem -= spike.
//
// R1-R5: five structures pinned ~88us / 2.3 TB/s (VALUBusy<=17% -> not issue).
// R6: XCD-segmented j-sweep, BLOCK=256, NT stores: ~79-80us (2.5 TB/s). Best.
// R7 FAILED (126us): per-thread 4-col chunk (pipeline collapsed, no TLP).
// R8 FAILED (88us): BLOCK=1024. R9 NULL (80.5us): inter-stream alias rotation.
// R10 NULL (82.4us): regular stores == NT stores (FETCH unchanged 65.5MB).
// R11 (resubmit after broker timeout): WAVE-PER-STREAM. Last untested
//   structural variable vs the 6.3 TB/s copy ubench: streams per requester.
//   All prior kernels had each wave interleave 4R+4W streams 32MB apart;
//   copy's waves touch 1R+1W contiguous runs. Here wave w exclusively loads
//   stream w (contiguous 4KiB run) -> LDS -> columns scanned per-thread ->
//   LDS -> wave w stores stream w (contiguous run). Per-requester
//   single-stream on both sides.

constexpr int T_STEPS = 4;
constexpr int BLOCK   = 256;   // 4 waves == T_STEPS streams
constexpr int NXCD    = 8;

typedef float v4f __attribute__((ext_vector_type(4)));

// Exact spike via fp32 bit ordering (thresh > 0 normal, mem non-NaN):
// positive fp32 compare == int compare of bits; thr75[k] bits = b75_0 - k*2^23;
// k* = max(0, ceil((b75_0 - bits(mem)) / 2^23)); spike bits = bth0 - k*·2^23;
// mem < thr75[7] (incl. mem<=0, signed cmp) -> 0.  Verified absmax=0 R5-R10.
__device__ __forceinline__ float spike_of(float mem, int b75_0, int b75_7, int bth0) {
    int u = __float_as_int(mem);
    int d = (int)((unsigned)b75_0 - (unsigned)u);
    int k = (int)((unsigned)d + 0x7fffffu) >> 23;
    k = k > 0 ? k : 0;
    int sb = bth0 - (k << 23);
    return (u >= b75_7) ? __int_as_float(sb) : 0.0f;
}

__global__ __launch_bounds__(BLOCK) void snn_mth_kernel(
    const float* __restrict__ x,
    const float* __restrict__ p_thresh,
    float* __restrict__ out,
    int s4)   // float4 columns per timestep
{
    const float thresh = *p_thresh;
    const int bth0  = __float_as_int(thresh);
    const int b75_0 = __float_as_int(0.75f * thresh);
    const int b75_7 = b75_0 - 7 * 0x800000;

    const v4f* __restrict__ xv = reinterpret_cast<const v4f*>(x);
    v4f* __restrict__ ov = reinterpret_cast<v4f*>(out);

    __shared__ v4f lds[T_STEPS][BLOCK];   // 16 KiB; reused for in and out

    // XCD-segmented mapping (R6): segment = b % NXCD (matches CP round-robin
    // block->XCD dispatch), slot = b / NXCD sweeps within the segment.
    const int seg_cols   = s4 / (NXCD * BLOCK) * BLOCK;
    const int seg_blocks = seg_cols / BLOCK;
    const int main_blocks = seg_blocks * NXCD;

    const int b    = blockIdx.x;
    const int tid  = threadIdx.x;
    const int wave = tid >> 6;            // 0..3 == stream id
    const int lane = tid & 63;
    const size_t n = (size_t)s4;

    if (b < main_blocks) {
        const int xcd  = b % NXCD;
        const int slot = b / NXCD;
        const size_t col0 = (size_t)xcd * seg_cols + (size_t)slot * BLOCK;

        // ---- load: wave w reads stream w's 256 columns as one contiguous
        // 4KiB run (4 independent 1KiB wave-loads, all in flight).
        const size_t sbase = (size_t)wave * n + col0;
#pragma unroll
        for (int i = 0; i < BLOCK / 64; ++i)
            lds[wave][i * 64 + lane] = xv[sbase + i * 64 + lane];
        __syncthreads();

        // ---- compute: thread tid scans its column from LDS.
        v4f xc[T_STEPS];
#pragma unroll
        for (int t = 0; t < T_STEPS; ++t)
            xc[t] = lds[t][tid];

        v4f sp[T_STEPS];
#pragma unroll
        for (int e = 0; e < 4; ++e) {
            float mem = xc[0][e];
            float s0 = spike_of(mem, b75_0, b75_7, bth0);
            sp[0][e] = s0;
            mem = mem - s0 + xc[1][e];
            float s1 = spike_of(mem, b75_0, b75_7, bth0);
            sp[1][e] = s1;
            mem = mem - s1 + xc[2][e];
            float s2 = spike_of(mem, b75_0, b75_7, bth0);
            sp[2][e] = s2;
            mem = mem - s2 + xc[3][e];
            sp[3][e] = spike_of(mem, b75_0, b75_7, bth0);
        }

        __syncthreads();   // WAR: everyone done reading lds before overwrite
#pragma unroll
        for (int t = 0; t < T_STEPS; ++t)
            lds[t][tid] = sp[t];
        __syncthreads();

        // ---- store: wave w writes stream w's contiguous run (NT, per R6).
#pragma unroll
        for (int i = 0; i < BLOCK / 64; ++i)
            __builtin_nontemporal_store(lds[wave][i * 64 + lane],
                                        &ov[sbase + i * 64 + lane]);
    } else {
        // Tail (empty for the benchmark shape: s4 = 2^21 divides evenly).
        const size_t j = (size_t)NXCD * seg_cols + (size_t)(b - main_blocks) * BLOCK + tid;
        if (j >= n) return;
        v4f xc[T_STEPS];
#pragma unroll
        for (int t = 0; t < T_STEPS; ++t)
            xc[t] = xv[(size_t)t * n + j];
        v4f sp[T_STEPS];
#pragma unroll
        for (int e = 0; e < 4; ++e) {
            float mem = xc[0][e];
            float s0 = spike_of(mem, b75_0, b75_7, bth0);
            sp[0][e] = s0;
            mem = mem - s0 + xc[1][e];
            float s1 = spike_of(mem, b75_0, b75_7, bth0);
            sp[1][e] = s1;
            mem = mem - s1 + xc[2][e];
            float s2 = spike_of(mem, b75_0, b75_7, bth0);
            sp[2][e] = s2;
            mem = mem - s2 + xc[3][e];
            sp[3][e] = spike_of(mem, b75_0, b75_7, bth0);
        }
#pragma unroll
        for (int t = 0; t < T_STEPS; ++t)
            __builtin_nontemporal_store(sp[t], &ov[(size_t)t * n + j]);
    }
}

extern "C" void kernel_launch(void* const* d_in, const int* in_sizes, int n_in,
                              void* d_out, int out_size, void* d_ws, size_t ws_size,
                              hipStream_t stream) {
    const float* x = (const float*)d_in[0];
    const float* p_thresh = (const float*)d_in[1];
    float* out = (float*)d_out;

    const int total = in_sizes[0];          // T*B*C*H*W
    const int S = total / T_STEPS;          // spatial elements per timestep
    const int s4 = S >> 2;                  // float4 columns

    const int grid = (s4 + BLOCK - 1) / BLOCK;
    snn_mth_kernel<<<grid, BLOCK, 0, stream>>>(x, p_thresh, out, s4);
}